// Round 1
// baseline (277.774 us; speedup 1.0000x reference)
//
#include <hip/hip_runtime.h>
#include <math.h>

// Problem constants (from reference): images (32,512,512,3) f32, matrices (32,2,3) f32,
// output (32,224,224,3) f32.
constexpr int B  = 32;
constexpr int H  = 512;
constexpr int W  = 512;
constexpr int C  = 3;
constexpr int OH = 224;
constexpr int OW = 224;

// jax.image.resize(method="bilinear") == scale_and_translate with triangle kernel,
// antialias=True: kernel_scale = in/out = 16/7, sample_f = (i+0.5)*in/out - 0.5,
// weights w_j = max(0, 1 - |sample_f - j| * out/in) for j in [0,in), renormalized
// to sum 1 over the valid j. Support width 2*16/7 ≈ 4.57 -> at most 5 taps.

__global__ __launch_bounds__(256) void warp_resize(const float* __restrict__ img,
                                                   const float* __restrict__ mats,
                                                   float* __restrict__ out) {
    const int tid  = blockIdx.x * 256 + threadIdx.x;   // total = B*OH*OW, exact multiple of 256
    const int ox   = tid % OW;
    const int rest = tid / OW;
    const int oy   = rest % OH;
    const int b    = rest / OH;

    const float* M = mats + b * 6;
    const float m00 = M[0], m01 = M[1], m02 = M[2];
    const float m10 = M[3], m11 = M[4], m12 = M[5];

    const float s     = 512.0f / 224.0f;   // inv_scale == kernel_scale (downsampling)
    const float invks = 224.0f / 512.0f;

    const float sfy = (oy + 0.5f) * s - 0.5f;
    const float sfx = (ox + 0.5f) * s - 0.5f;
    const int   jy0 = (int)ceilf(sfy - s);
    const int   jx0 = (int)ceilf(sfx - s);

    float wy[5], wx[5];
    float sy = 0.0f, sx = 0.0f;
#pragma unroll
    for (int k = 0; k < 5; ++k) {
        const int jy = jy0 + k;
        float vy = 1.0f - fabsf(sfy - (float)jy) * invks;
        vy = (jy >= 0 && jy < H) ? fmaxf(vy, 0.0f) : 0.0f;
        wy[k] = vy; sy += vy;
        const int jx = jx0 + k;
        float vx = 1.0f - fabsf(sfx - (float)jx) * invks;
        vx = (jx >= 0 && jx < W) ? fmaxf(vx, 0.0f) : 0.0f;
        wx[k] = vx; sx += vx;
    }
    const float rnorm = 1.0f / (sy * sx);

    const float* imgb = img + (size_t)b * H * W * C;

    float a0 = 0.0f, a1 = 0.0f, a2 = 0.0f;
    for (int ky = 0; ky < 5; ++ky) {
        const float wyk = wy[ky];
        if (wyk == 0.0f) continue;
        const float yf = (float)(jy0 + ky);
        // affine warp: output (y,x) -> source (src_y, src_x)
        const float cy = m00 * yf + m02;
        const float cx = m10 * yf + m12;
        for (int kx = 0; kx < 5; ++kx) {
            const float wgt = wyk * wx[kx];
            if (wgt == 0.0f) continue;
            const float xf    = (float)(jx0 + kx);
            const float src_y = cy + m01 * xf;
            const float src_x = cx + m11 * xf;
            const float fy0 = floorf(src_y);
            const float fx0 = floorf(src_x);
            const float fy  = src_y - fy0;
            const float fx  = src_x - fx0;
            const int   iy0 = (int)fy0;
            const int   ix0 = (int)fx0;

            float v[4][3];
#pragma unroll
            for (int t = 0; t < 4; ++t) {
                const int yi = iy0 + (t >> 1);
                const int xi = ix0 + (t & 1);
                if (yi >= 0 && yi < H && xi >= 0 && xi < W) {
                    const float* p = imgb + ((size_t)yi * W + xi) * C;
                    v[t][0] = p[0]; v[t][1] = p[1]; v[t][2] = p[2];
                } else {
                    v[t][0] = 0.0f; v[t][1] = 0.0f; v[t][2] = 0.0f;
                }
            }
            const float w00 = (1.0f - fy) * (1.0f - fx);
            const float w01 = (1.0f - fy) * fx;
            const float w10 = fy * (1.0f - fx);
            const float w11 = fy * fx;
            a0 += wgt * (v[0][0] * w00 + v[1][0] * w01 + v[2][0] * w10 + v[3][0] * w11);
            a1 += wgt * (v[0][1] * w00 + v[1][1] * w01 + v[2][1] * w10 + v[3][1] * w11);
            a2 += wgt * (v[0][2] * w00 + v[1][2] * w01 + v[2][2] * w10 + v[3][2] * w11);
        }
    }

    float* o = out + (size_t)tid * 3;
    o[0] = a0 * rnorm;
    o[1] = a1 * rnorm;
    o[2] = a2 * rnorm;
}

extern "C" void kernel_launch(void* const* d_in, const int* in_sizes, int n_in,
                              void* d_out, int out_size, void* d_ws, size_t ws_size,
                              hipStream_t stream) {
    const float* img  = (const float*)d_in[0];
    const float* mats = (const float*)d_in[1];
    float*       out  = (float*)d_out;

    const int total  = B * OH * OW;   // 1,605,632
    const int blocks = total / 256;   // 6272 (exact)
    hipLaunchKernelGGL(warp_resize, dim3(blocks), dim3(256), 0, stream, img, mats, out);
}

// Round 2
// 164.334 us; speedup vs baseline: 1.6903x; 1.6903x over previous
//
#include <hip/hip_runtime.h>
#include <math.h>

// images (32,512,512,3) f32, matrices (32,2,3) f32 -> out (32,224,224,3) f32.
// Fused: per-sample affine warp (bilinear, zero pad) + antialiased bilinear
// resize 512->224 (triangle kernel, kernel_scale=16/7, renormalized weights).
constexpr int B  = 32;
constexpr int H  = 512;
constexpr int W  = 512;
constexpr int C  = 3;
constexpr int OH = 224;
constexpr int OW = 224;

constexpr int TILE = 16;         // output tile side
constexpr int WIN  = 40;         // warped-window side covering a TILE of outputs
constexpr int NT   = OH / TILE;  // 14 tiles per axis

__global__ __launch_bounds__(256) void warp_resize_tiled(const float* __restrict__ img,
                                                         const float* __restrict__ mats,
                                                         float* __restrict__ out) {
    // Stage buffers: warped window, then vertically-resized rows.
    __shared__ float sW[WIN][WIN * 3];   // 19200 B
    __shared__ float sV[TILE][WIN * 3];  //  7680 B

    const int bid = blockIdx.x;
    const int b   = bid / (NT * NT);
    const int rm  = bid % (NT * NT);
    const int ty  = rm / NT;
    const int tx  = rm % NT;
    const int tid = threadIdx.x;

    const float* Mp = mats + b * 6;
    const float m00 = Mp[0], m01 = Mp[1], m02 = Mp[2];
    const float m10 = Mp[3], m11 = Mp[4], m12 = Mp[5];

    const float s     = 512.0f / 224.0f;   // kernel_scale (downsample)
    const float invks = 224.0f / 512.0f;

    const int oy_base = ty * TILE;
    const int ox_base = tx * TILE;
    const int jy0 = (int)ceilf((oy_base + 0.5f) * s - 0.5f - s);  // window origin (may be <0)
    const int jx0 = (int)ceilf((ox_base + 0.5f) * s - 0.5f - s);

    const float* imgb = img + (size_t)b * H * W * C;

    // ---- Stage 1: warp 40x40 window into LDS (bilinear gather, zero pad) ----
    for (int e = tid; e < WIN * WIN; e += 256) {
        const int r = e / WIN;
        const int c = e % WIN;
        const float yf = (float)(jy0 + r);
        const float xf = (float)(jx0 + c);
        const float src_y = m00 * yf + m01 * xf + m02;
        const float src_x = m10 * yf + m11 * xf + m12;
        const float fy0 = floorf(src_y);
        const float fx0 = floorf(src_x);
        const float fy  = src_y - fy0;
        const float fx  = src_x - fx0;
        const int iy0 = (int)fy0;
        const int ix0 = (int)fx0;

        float v[4][3];
#pragma unroll
        for (int t = 0; t < 4; ++t) {
            const int yi = iy0 + (t >> 1);
            const int xi = ix0 + (t & 1);
            if (yi >= 0 && yi < H && xi >= 0 && xi < W) {
                const float* p = imgb + ((size_t)yi * W + xi) * C;
                v[t][0] = p[0]; v[t][1] = p[1]; v[t][2] = p[2];
            } else {
                v[t][0] = 0.0f; v[t][1] = 0.0f; v[t][2] = 0.0f;
            }
        }
        const float w00 = (1.0f - fy) * (1.0f - fx);
        const float w01 = (1.0f - fy) * fx;
        const float w10 = fy * (1.0f - fx);
        const float w11 = fy * fx;
        sW[r][c * 3 + 0] = v[0][0] * w00 + v[1][0] * w01 + v[2][0] * w10 + v[3][0] * w11;
        sW[r][c * 3 + 1] = v[0][1] * w00 + v[1][1] * w01 + v[2][1] * w10 + v[3][1] * w11;
        sW[r][c * 3 + 2] = v[0][2] * w00 + v[1][2] * w01 + v[2][2] * w10 + v[3][2] * w11;
    }
    __syncthreads();

    // ---- Stage 2: vertical 5-tap resize -> sV[16][40*3] ----
    for (int e = tid; e < TILE * WIN; e += 256) {
        const int r = e / WIN;   // local output row
        const int c = e % WIN;   // window column
        const int oy = oy_base + r;
        const float sfy = (oy + 0.5f) * s - 0.5f;
        const int j0 = (int)ceilf(sfy - s);
        float wk[5];
        float sum = 0.0f;
#pragma unroll
        for (int k = 0; k < 5; ++k) {
            const int jy = j0 + k;
            float wv = 1.0f - fabsf(sfy - (float)jy) * invks;
            wv = (jy >= 0 && jy < H) ? fmaxf(wv, 0.0f) : 0.0f;
            wk[k] = wv; sum += wv;
        }
        const float inv = 1.0f / sum;
        float a0 = 0.0f, a1 = 0.0f, a2 = 0.0f;
#pragma unroll
        for (int k = 0; k < 5; ++k) {
            const int rr = j0 + k - jy0;   // in [0, 39] by construction
            const float wv = wk[k];
            a0 += wv * sW[rr][c * 3 + 0];
            a1 += wv * sW[rr][c * 3 + 1];
            a2 += wv * sW[rr][c * 3 + 2];
        }
        sV[r][c * 3 + 0] = a0 * inv;
        sV[r][c * 3 + 1] = a1 * inv;
        sV[r][c * 3 + 2] = a2 * inv;
    }
    __syncthreads();

    // ---- Stage 3: horizontal 5-tap, one thread per output pixel ----
    const int oxl = tid % TILE;
    const int oyl = tid / TILE;
    const int ox  = ox_base + oxl;
    const int oy  = oy_base + oyl;
    const float sfx = (ox + 0.5f) * s - 0.5f;
    const int j0 = (int)ceilf(sfx - s);
    float wk[5];
    float sum = 0.0f;
#pragma unroll
    for (int k = 0; k < 5; ++k) {
        const int jx = j0 + k;
        float wv = 1.0f - fabsf(sfx - (float)jx) * invks;
        wv = (jx >= 0 && jx < W) ? fmaxf(wv, 0.0f) : 0.0f;
        wk[k] = wv; sum += wv;
    }
    const float inv = 1.0f / sum;
    float a0 = 0.0f, a1 = 0.0f, a2 = 0.0f;
#pragma unroll
    for (int k = 0; k < 5; ++k) {
        const int cc = j0 + k - jx0;   // in [0, 39]
        const float wv = wk[k];
        a0 += wv * sV[oyl][cc * 3 + 0];
        a1 += wv * sV[oyl][cc * 3 + 1];
        a2 += wv * sV[oyl][cc * 3 + 2];
    }
    float* o = out + (((size_t)b * OH + oy) * OW + ox) * 3;
    o[0] = a0 * inv;
    o[1] = a1 * inv;
    o[2] = a2 * inv;
}

extern "C" void kernel_launch(void* const* d_in, const int* in_sizes, int n_in,
                              void* d_out, int out_size, void* d_ws, size_t ws_size,
                              hipStream_t stream) {
    const float* img  = (const float*)d_in[0];
    const float* mats = (const float*)d_in[1];
    float*       out  = (float*)d_out;

    const int blocks = B * NT * NT;   // 32 * 196 = 6272
    hipLaunchKernelGGL(warp_resize_tiled, dim3(blocks), dim3(256), 0, stream, img, mats, out);
}

// Round 3
// 162.588 us; speedup vs baseline: 1.7085x; 1.0107x over previous
//
#include <hip/hip_runtime.h>
#include <math.h>

// images (32,512,512,3) f32, matrices (32,2,3) f32 -> out (32,224,224,3) f32.
// Fused: per-sample affine warp (bilinear, zero pad) + antialiased bilinear
// resize 512->224 (triangle kernel, kernel_scale=16/7, renormalized weights).
constexpr int B  = 32;
constexpr int H  = 512;
constexpr int W  = 512;
constexpr int C  = 3;
constexpr int OH = 224;
constexpr int OW = 224;

constexpr int TILE = 16;         // output tile side
constexpr int WIN  = 40;         // warped-window side covering a TILE of outputs
constexpr int NT   = OH / TILE;  // 14 tiles per axis
constexpr int NB   = B * NT * NT;  // 6272 blocks (divisible by 8)
constexpr int THREADS = 320;     // 5 waves; 1600/320=5, 640/320=2 exact

__global__ __launch_bounds__(THREADS) void warp_resize_tiled(const float* __restrict__ img,
                                                             const float* __restrict__ mats,
                                                             float* __restrict__ out) {
    __shared__ float sW[WIN][WIN * 3];   // 19200 B warped window
    __shared__ float sV[TILE][WIN * 3];  //  7680 B vertical-resized

    // XCD-aware bijective swizzle: each XCD gets 784 consecutive logical blocks
    // (= 4 whole images, 3 MB each -> fits the XCD's 4 MB L2).
    int bid = (int)blockIdx.x;
    bid = (bid & 7) * (NB / 8) + (bid >> 3);

    const int b   = bid / (NT * NT);
    const int rm  = bid % (NT * NT);
    const int ty  = rm / NT;
    const int tx  = rm % NT;
    const int tid = (int)threadIdx.x;

    const float* Mp = mats + b * 6;
    const float m00 = Mp[0], m01 = Mp[1], m02 = Mp[2];
    const float m10 = Mp[3], m11 = Mp[4], m12 = Mp[5];

    const float s     = 512.0f / 224.0f;   // kernel_scale (downsample)
    const float invks = 224.0f / 512.0f;

    const int oy_base = ty * TILE;
    const int ox_base = tx * TILE;
    const int jy0 = (int)ceilf((oy_base + 0.5f) * s - 0.5f - s);  // window origin
    const int jx0 = (int)ceilf((ox_base + 0.5f) * s - 0.5f - s);

    const float* imgb = img + (size_t)b * H * W * C;

    // ---- Interior test: affine bbox of the 4 window corners ----
    const float y_lo = (float)jy0, y_hi = (float)(jy0 + WIN - 1);
    const float x_lo = (float)jx0, x_hi = (float)(jx0 + WIN - 1);
    float cy00 = m00 * y_lo + m01 * x_lo + m02;
    float cy01 = m00 * y_lo + m01 * x_hi + m02;
    float cy10 = m00 * y_hi + m01 * x_lo + m02;
    float cy11 = m00 * y_hi + m01 * x_hi + m02;
    float cx00 = m10 * y_lo + m11 * x_lo + m12;
    float cx01 = m10 * y_lo + m11 * x_hi + m12;
    float cx10 = m10 * y_hi + m11 * x_lo + m12;
    float cx11 = m10 * y_hi + m11 * x_hi + m12;
    const float miny = fminf(fminf(cy00, cy01), fminf(cy10, cy11));
    const float maxy = fmaxf(fmaxf(cy00, cy01), fmaxf(cy10, cy11));
    const float minx = fminf(fminf(cx00, cx01), fminf(cx10, cx11));
    const float maxx = fmaxf(fmaxf(cx00, cx01), fmaxf(cx10, cx11));
    const bool interior = (miny >= 0.01f) && (maxy <= 510.9f) &&
                          (minx >= 0.01f) && (maxx <= 510.9f);

    // ---- Stage 1: warp 40x40 window into LDS ----
    {
        const int c  = tid % WIN;          // loop-invariant column
        int       r  = tid / WIN;          // 0..7, += 8 per iter
        const float xf = (float)(jx0 + c);
        const float cY = m01 * xf + m02;   // src_y = m00*yf + cY
        const float cX = m11 * xf + m12;   // src_x = m10*yf + cX

        if (interior) {
#pragma unroll
            for (int it = 0; it < 5; ++it) {
                const float yf = (float)(jy0 + r);
                const float src_y = m00 * yf + cY;
                const float src_x = m10 * yf + cX;
                const float fy0 = floorf(src_y);
                const float fx0 = floorf(src_x);
                const float fy  = src_y - fy0;
                const float fx  = src_x - fx0;
                const int off = ((int)fy0 * W + (int)fx0) * 3;
                const float* p0 = imgb + off;           // row iy0: 6 floats
                const float* p1 = p0 + W * 3;           // row iy0+1
                const float a0 = p0[0], a1 = p0[1], a2 = p0[2];
                const float a3 = p0[3], a4 = p0[4], a5 = p0[5];
                const float b0 = p1[0], b1 = p1[1], b2 = p1[2];
                const float b3 = p1[3], b4 = p1[4], b5 = p1[5];
                const float w00 = (1.0f - fy) * (1.0f - fx);
                const float w01 = (1.0f - fy) * fx;
                const float w10 = fy * (1.0f - fx);
                const float w11 = fy * fx;
                sW[r][c * 3 + 0] = a0 * w00 + a3 * w01 + b0 * w10 + b3 * w11;
                sW[r][c * 3 + 1] = a1 * w00 + a4 * w01 + b1 * w10 + b4 * w11;
                sW[r][c * 3 + 2] = a2 * w00 + a5 * w01 + b2 * w10 + b5 * w11;
                r += 8;
            }
        } else {
#pragma unroll
            for (int it = 0; it < 5; ++it) {
                const float yf = (float)(jy0 + r);
                const float src_y = m00 * yf + cY;
                const float src_x = m10 * yf + cX;
                const float fy0 = floorf(src_y);
                const float fx0 = floorf(src_x);
                const float fy  = src_y - fy0;
                const float fx  = src_x - fx0;
                const int iy0 = (int)fy0;
                const int ix0 = (int)fx0;
                float v[4][3];
#pragma unroll
                for (int t = 0; t < 4; ++t) {
                    const int yi = iy0 + (t >> 1);
                    const int xi = ix0 + (t & 1);
                    if (yi >= 0 && yi < H && xi >= 0 && xi < W) {
                        const float* p = imgb + (yi * W + xi) * 3;
                        v[t][0] = p[0]; v[t][1] = p[1]; v[t][2] = p[2];
                    } else {
                        v[t][0] = 0.0f; v[t][1] = 0.0f; v[t][2] = 0.0f;
                    }
                }
                const float w00 = (1.0f - fy) * (1.0f - fx);
                const float w01 = (1.0f - fy) * fx;
                const float w10 = fy * (1.0f - fx);
                const float w11 = fy * fx;
                sW[r][c * 3 + 0] = v[0][0] * w00 + v[1][0] * w01 + v[2][0] * w10 + v[3][0] * w11;
                sW[r][c * 3 + 1] = v[0][1] * w00 + v[1][1] * w01 + v[2][1] * w10 + v[3][1] * w11;
                sW[r][c * 3 + 2] = v[0][2] * w00 + v[1][2] * w01 + v[2][2] * w10 + v[3][2] * w11;
                r += 8;
            }
        }
    }
    __syncthreads();

    // ---- Stage 2: vertical 5-tap resize -> sV[16][40*3] ----
    {
        const int c = tid % WIN;           // window column (invariant)
        int       r = tid / WIN;           // 0..7, then +8
#pragma unroll
        for (int it = 0; it < 2; ++it) {
            const int oy = oy_base + r;
            const float sfy = (oy + 0.5f) * s - 0.5f;
            const int j0 = (int)ceilf(sfy - s);
            float wk[5];
            float sum = 0.0f;
#pragma unroll
            for (int k = 0; k < 5; ++k) {
                const int jy = j0 + k;
                float wv = 1.0f - fabsf(sfy - (float)jy) * invks;
                wv = (jy >= 0 && jy < H) ? fmaxf(wv, 0.0f) : 0.0f;
                wk[k] = wv; sum += wv;
            }
            const float inv = 1.0f / sum;
            float a0 = 0.0f, a1 = 0.0f, a2 = 0.0f;
#pragma unroll
            for (int k = 0; k < 5; ++k) {
                const int rr = j0 + k - jy0;   // in [0, 39]
                const float wv = wk[k];
                a0 += wv * sW[rr][c * 3 + 0];
                a1 += wv * sW[rr][c * 3 + 1];
                a2 += wv * sW[rr][c * 3 + 2];
            }
            sV[r][c * 3 + 0] = a0 * inv;
            sV[r][c * 3 + 1] = a1 * inv;
            sV[r][c * 3 + 2] = a2 * inv;
            r += 8;
        }
    }
    __syncthreads();

    // ---- Stage 3: horizontal 5-tap, one thread per output pixel ----
    if (tid < TILE * TILE) {
        const int oxl = tid % TILE;
        const int oyl = tid / TILE;
        const int ox  = ox_base + oxl;
        const int oy  = oy_base + oyl;
        const float sfx = (ox + 0.5f) * s - 0.5f;
        const int j0 = (int)ceilf(sfx - s);
        float wk[5];
        float sum = 0.0f;
#pragma unroll
        for (int k = 0; k < 5; ++k) {
            const int jx = j0 + k;
            float wv = 1.0f - fabsf(sfx - (float)jx) * invks;
            wv = (jx >= 0 && jx < W) ? fmaxf(wv, 0.0f) : 0.0f;
            wk[k] = wv; sum += wv;
        }
        const float inv = 1.0f / sum;
        float a0 = 0.0f, a1 = 0.0f, a2 = 0.0f;
#pragma unroll
        for (int k = 0; k < 5; ++k) {
            const int cc = j0 + k - jx0;   // in [0, 39]
            const float wv = wk[k];
            a0 += wv * sV[oyl][cc * 3 + 0];
            a1 += wv * sV[oyl][cc * 3 + 1];
            a2 += wv * sV[oyl][cc * 3 + 2];
        }
        float* o = out + (((size_t)b * OH + oy) * OW + ox) * 3;
        o[0] = a0 * inv;
        o[1] = a1 * inv;
        o[2] = a2 * inv;
    }
}

extern "C" void kernel_launch(void* const* d_in, const int* in_sizes, int n_in,
                              void* d_out, int out_size, void* d_ws, size_t ws_size,
                              hipStream_t stream) {
    const float* img  = (const float*)d_in[0];
    const float* mats = (const float*)d_in[1];
    float*       out  = (float*)d_out;

    hipLaunchKernelGGL(warp_resize_tiled, dim3(NB), dim3(THREADS), 0, stream, img, mats, out);
}

// Round 4
// 161.092 us; speedup vs baseline: 1.7243x; 1.0093x over previous
//
#include <hip/hip_runtime.h>
#include <hip/hip_bf16.h>
#include <math.h>

// images (32,512,512,3) f32, matrices (32,2,3) f32 -> out (32,224,224,3) f32.
// Fused: per-sample affine warp (bilinear, zero pad) + antialiased bilinear
// resize 512->224 (triangle kernel, kernel_scale=16/7, renormalized weights).
constexpr int B  = 32;
constexpr int H  = 512;
constexpr int W  = 512;
constexpr int OH = 224;
constexpr int OW = 224;

constexpr int TILE = 16;           // output tile side
constexpr int WIN  = 40;           // warped-window side covering a TILE of outputs
constexpr int NT   = OH / TILE;    // 14
constexpr int NB   = B * NT * NT;  // 6272 (divisible by 8)
constexpr int THREADS = 256;       // 4 waves; 8 blocks/CU -> 32 waves/CU (100%)

__global__ __launch_bounds__(THREADS, 8) void warp_resize_tiled(const float* __restrict__ img,
                                                                const float* __restrict__ mats,
                                                                float* __restrict__ out) {
    // Warped window in bf16 SoA channel planes (halves LDS footprint + traffic):
    __shared__ __hip_bfloat16 sWp[3][WIN][WIN];   // 9600 B
    __shared__ float          sV[TILE][WIN * 3];  // 7680 B   (total 17280 B -> 8 blocks/CU)

    // XCD-aware bijective swizzle: 784 consecutive logical blocks per XCD
    // (~1 image in flight per XCD L2).
    int bid = (int)blockIdx.x;
    bid = (bid & 7) * (NB / 8) + (bid >> 3);

    const int b   = bid / (NT * NT);
    const int rm  = bid % (NT * NT);
    const int ty  = rm / NT;
    const int tx  = rm % NT;
    const int tid = (int)threadIdx.x;

    const float* Mp = mats + b * 6;
    const float m00 = Mp[0], m01 = Mp[1], m02 = Mp[2];
    const float m10 = Mp[3], m11 = Mp[4], m12 = Mp[5];

    const float s     = 512.0f / 224.0f;   // kernel_scale (downsample)
    const float invks = 224.0f / 512.0f;

    const int oy_base = ty * TILE;
    const int ox_base = tx * TILE;
    const int jy0 = (int)ceilf((oy_base + 0.5f) * s - 0.5f - s);  // window origin
    const int jx0 = (int)ceilf((ox_base + 0.5f) * s - 0.5f - s);

    const float* imgb = img + (size_t)b * H * W * 3;

    // ---- Interior test (block-uniform): affine bbox of the 4 window corners ----
    const float y_lo = (float)jy0, y_hi = (float)(jy0 + WIN - 1);
    const float x_lo = (float)jx0, x_hi = (float)(jx0 + WIN - 1);
    const float cy00 = m00 * y_lo + m01 * x_lo + m02;
    const float cy01 = m00 * y_lo + m01 * x_hi + m02;
    const float cy10 = m00 * y_hi + m01 * x_lo + m02;
    const float cy11 = m00 * y_hi + m01 * x_hi + m02;
    const float cx00 = m10 * y_lo + m11 * x_lo + m12;
    const float cx01 = m10 * y_lo + m11 * x_hi + m12;
    const float cx10 = m10 * y_hi + m11 * x_lo + m12;
    const float cx11 = m10 * y_hi + m11 * x_hi + m12;
    const float miny = fminf(fminf(cy00, cy01), fminf(cy10, cy11));
    const float maxy = fmaxf(fmaxf(cy00, cy01), fmaxf(cy10, cy11));
    const float minx = fminf(fminf(cx00, cx01), fminf(cx10, cx11));
    const float maxx = fmaxf(fmaxf(cx00, cx01), fmaxf(cx10, cx11));
    const bool interior = (miny >= 0.01f) && (maxy <= 510.9f) &&
                          (minx >= 0.01f) && (maxx <= 510.9f);

    // ---- Stage 1: warp 40x40 window into LDS (bilinear gather, zero pad) ----
    if (interior) {
        for (int e = tid; e < WIN * WIN; e += THREADS) {
            const int r = e / WIN;
            const int c = e - r * WIN;
            const float yf = (float)(jy0 + r);
            const float xf = (float)(jx0 + c);
            const float src_y = m00 * yf + m01 * xf + m02;
            const float src_x = m10 * yf + m11 * xf + m12;
            const float fy0 = floorf(src_y);
            const float fx0 = floorf(src_x);
            const float fy  = src_y - fy0;
            const float fx  = src_x - fx0;
            const int off = ((int)fy0 * W + (int)fx0) * 3;
            const float* p0 = imgb + off;       // 6 consecutive floats (2 px)
            const float* p1 = p0 + W * 3;
            const float a0 = p0[0], a1 = p0[1], a2 = p0[2];
            const float a3 = p0[3], a4 = p0[4], a5 = p0[5];
            const float b0 = p1[0], b1 = p1[1], b2 = p1[2];
            const float b3 = p1[3], b4 = p1[4], b5 = p1[5];
            const float w00 = (1.0f - fy) * (1.0f - fx);
            const float w01 = (1.0f - fy) * fx;
            const float w10 = fy * (1.0f - fx);
            const float w11 = fy * fx;
            sWp[0][r][c] = __float2bfloat16(a0 * w00 + a3 * w01 + b0 * w10 + b3 * w11);
            sWp[1][r][c] = __float2bfloat16(a1 * w00 + a4 * w01 + b1 * w10 + b4 * w11);
            sWp[2][r][c] = __float2bfloat16(a2 * w00 + a5 * w01 + b2 * w10 + b5 * w11);
        }
    } else {
        for (int e = tid; e < WIN * WIN; e += THREADS) {
            const int r = e / WIN;
            const int c = e - r * WIN;
            const float yf = (float)(jy0 + r);
            const float xf = (float)(jx0 + c);
            const float src_y = m00 * yf + m01 * xf + m02;
            const float src_x = m10 * yf + m11 * xf + m12;
            const float fy0 = floorf(src_y);
            const float fx0 = floorf(src_x);
            const float fy  = src_y - fy0;
            const float fx  = src_x - fx0;
            const int iy0 = (int)fy0;
            const int ix0 = (int)fx0;
            float v[4][3];
#pragma unroll
            for (int t = 0; t < 4; ++t) {
                const int yi = iy0 + (t >> 1);
                const int xi = ix0 + (t & 1);
                if (yi >= 0 && yi < H && xi >= 0 && xi < W) {
                    const float* p = imgb + (yi * W + xi) * 3;
                    v[t][0] = p[0]; v[t][1] = p[1]; v[t][2] = p[2];
                } else {
                    v[t][0] = 0.0f; v[t][1] = 0.0f; v[t][2] = 0.0f;
                }
            }
            const float w00 = (1.0f - fy) * (1.0f - fx);
            const float w01 = (1.0f - fy) * fx;
            const float w10 = fy * (1.0f - fx);
            const float w11 = fy * fx;
            sWp[0][r][c] = __float2bfloat16(v[0][0] * w00 + v[1][0] * w01 + v[2][0] * w10 + v[3][0] * w11);
            sWp[1][r][c] = __float2bfloat16(v[0][1] * w00 + v[1][1] * w01 + v[2][1] * w10 + v[3][1] * w11);
            sWp[2][r][c] = __float2bfloat16(v[0][2] * w00 + v[1][2] * w01 + v[2][2] * w10 + v[3][2] * w11);
        }
    }
    __syncthreads();

    // ---- Stage 2: vertical 5-tap resize -> sV[16][40*3] ----
    for (int e = tid; e < TILE * WIN; e += THREADS) {
        const int r = e / WIN;               // local output row
        const int c = e - r * WIN;           // window column
        const int oy = oy_base + r;
        const float sfy = (oy + 0.5f) * s - 0.5f;
        const int j0 = (int)ceilf(sfy - s);
        float wk[5];
        float sum = 0.0f;
#pragma unroll
        for (int k = 0; k < 5; ++k) {
            const int jy = j0 + k;
            float wv = 1.0f - fabsf(sfy - (float)jy) * invks;
            wv = (jy >= 0 && jy < H) ? fmaxf(wv, 0.0f) : 0.0f;
            wk[k] = wv; sum += wv;
        }
        const float inv = 1.0f / sum;
        float a0 = 0.0f, a1 = 0.0f, a2 = 0.0f;
#pragma unroll
        for (int k = 0; k < 5; ++k) {
            const int rr = j0 + k - jy0;     // in [0, 39]
            const float wv = wk[k];
            a0 += wv * __bfloat162float(sWp[0][rr][c]);
            a1 += wv * __bfloat162float(sWp[1][rr][c]);
            a2 += wv * __bfloat162float(sWp[2][rr][c]);
        }
        sV[r][c * 3 + 0] = a0 * inv;
        sV[r][c * 3 + 1] = a1 * inv;
        sV[r][c * 3 + 2] = a2 * inv;
    }
    __syncthreads();

    // ---- Stage 3: horizontal 5-tap, one thread per output pixel (256 exact) ----
    {
        const int oxl = tid % TILE;
        const int oyl = tid / TILE;
        const int ox  = ox_base + oxl;
        const int oy  = oy_base + oyl;
        const float sfx = (ox + 0.5f) * s - 0.5f;
        const int j0 = (int)ceilf(sfx - s);
        float wk[5];
        float sum = 0.0f;
#pragma unroll
        for (int k = 0; k < 5; ++k) {
            const int jx = j0 + k;
            float wv = 1.0f - fabsf(sfx - (float)jx) * invks;
            wv = (jx >= 0 && jx < W) ? fmaxf(wv, 0.0f) : 0.0f;
            wk[k] = wv; sum += wv;
        }
        const float inv = 1.0f / sum;
        float a0 = 0.0f, a1 = 0.0f, a2 = 0.0f;
#pragma unroll
        for (int k = 0; k < 5; ++k) {
            const int cc = j0 + k - jx0;     // in [0, 39]
            const float wv = wk[k];
            a0 += wv * sV[oyl][cc * 3 + 0];
            a1 += wv * sV[oyl][cc * 3 + 1];
            a2 += wv * sV[oyl][cc * 3 + 2];
        }
        float* o = out + (((size_t)b * OH + oy) * OW + ox) * 3;
        o[0] = a0 * inv;
        o[1] = a1 * inv;
        o[2] = a2 * inv;
    }
}

extern "C" void kernel_launch(void* const* d_in, const int* in_sizes, int n_in,
                              void* d_out, int out_size, void* d_ws, size_t ws_size,
                              hipStream_t stream) {
    const float* img  = (const float*)d_in[0];
    const float* mats = (const float*)d_in[1];
    float*       out  = (float*)d_out;

    hipLaunchKernelGGL(warp_resize_tiled, dim3(NB), dim3(THREADS), 0, stream, img, mats, out);
}

// Round 5
// 158.417 us; speedup vs baseline: 1.7534x; 1.0169x over previous
//
#include <hip/hip_runtime.h>
#include <hip/hip_bf16.h>
#include <math.h>

// images (32,512,512,3) f32, matrices (32,2,3) f32 -> out (32,224,224,3) f32.
// Fused: per-sample affine warp (bilinear, zero pad) + antialiased bilinear
// resize 512->224 (triangle kernel, kernel_scale=16/7, renormalized weights).
constexpr int B  = 32;
constexpr int H  = 512;
constexpr int W  = 512;
constexpr int OH = 224;
constexpr int OW = 224;

constexpr int TILE = 16;           // output tile side
constexpr int WIN  = 40;           // warped-window side covering a TILE of outputs
constexpr int NT   = OH / TILE;    // 14
constexpr int NB   = B * NT * NT;  // 6272 (divisible by 8)
constexpr int THREADS = 256;

union BfPack { __hip_bfloat162 h; unsigned u; };

static __device__ inline unsigned pack_bf2(float a, float b) {
    BfPack p; p.h = __float22bfloat162_rn(make_float2(a, b));
    return p.u;   // compiler emits v_cvt_pk_bf16_f32
}
static __device__ inline unsigned pack_bf1(float a) {
    BfPack p; p.h = __float22bfloat162_rn(make_float2(a, 0.0f));
    return p.u;
}
static __device__ inline float lo_bf(unsigned q) { return __uint_as_float(q << 16); }
static __device__ inline float hi_bf(unsigned q) { return __uint_as_float(q & 0xffff0000u); }

__global__ __launch_bounds__(THREADS, 8) void warp_resize_tiled(const float* __restrict__ img,
                                                                const float* __restrict__ mats,
                                                                float* __restrict__ out) {
    // Packed warped window: per px, q.x = bf16(ch0)|bf16(ch1)<<16, q.y = bf16(ch2).
    __shared__ uint2 sW[WIN][WIN];   // 12800 B
    __shared__ uint2 sV[TILE][WIN];  //  5120 B
    __shared__ float wyt[TILE][5], wxt[TILE][5];   // normalized tap weights
    __shared__ int   jyt[TILE], jxt[TILE];         // first tap, window-relative
    // total 18688 B -> 8 blocks/CU

    // XCD-aware bijective swizzle (6272 % 8 == 0).
    int bid = (int)blockIdx.x;
    bid = (bid & 7) * (NB / 8) + (bid >> 3);

    const int b   = bid / (NT * NT);
    const int rm  = bid % (NT * NT);
    const int ty  = rm / NT;
    const int tx  = rm % NT;
    const int tid = (int)threadIdx.x;

    const float* Mp = mats + b * 6;
    const float m00 = Mp[0], m01 = Mp[1], m02 = Mp[2];
    const float m10 = Mp[3], m11 = Mp[4], m12 = Mp[5];

    const float s     = 512.0f / 224.0f;   // kernel_scale (downsample)
    const float invks = 224.0f / 512.0f;

    const int oy_base = ty * TILE;
    const int ox_base = tx * TILE;
    const int jy0 = (int)ceilf((oy_base + 0.5f) * s - 0.5f - s);  // window origin
    const int jx0 = (int)ceilf((ox_base + 0.5f) * s - 0.5f - s);

    const float* imgb = img + (size_t)b * H * W * 3;

    // ---- Weight tables: 16 y-sets + 16 x-sets, normalized (threads 0..31) ----
    if (tid < 2 * TILE) {
        const bool isx = tid >= TILE;
        const int  i   = isx ? tid - TILE : tid;
        const int  ob  = isx ? ox_base : oy_base;
        const int  jw0 = isx ? jx0 : jy0;
        const float sf = ((float)(ob + i) + 0.5f) * s - 0.5f;
        const int  j0 = (int)ceilf(sf - s);
        float w[5]; float sum = 0.0f;
#pragma unroll
        for (int k = 0; k < 5; ++k) {
            const int j = j0 + k;
            float wv = 1.0f - fabsf(sf - (float)j) * invks;
            wv = (j >= 0 && j < H) ? fmaxf(wv, 0.0f) : 0.0f;
            w[k] = wv; sum += wv;
        }
        const float inv = 1.0f / sum;
        if (isx) {
            jxt[i] = j0 - jw0;
#pragma unroll
            for (int k = 0; k < 5; ++k) wxt[i][k] = w[k] * inv;
        } else {
            jyt[i] = j0 - jw0;
#pragma unroll
            for (int k = 0; k < 5; ++k) wyt[i][k] = w[k] * inv;
        }
    }

    // ---- Interior test (block-uniform): affine bbox of the 4 window corners ----
    const float y_lo = (float)jy0, y_hi = (float)(jy0 + WIN - 1);
    const float x_lo = (float)jx0, x_hi = (float)(jx0 + WIN - 1);
    const float cy00 = m00 * y_lo + m01 * x_lo + m02;
    const float cy01 = m00 * y_lo + m01 * x_hi + m02;
    const float cy10 = m00 * y_hi + m01 * x_lo + m02;
    const float cy11 = m00 * y_hi + m01 * x_hi + m02;
    const float cx00 = m10 * y_lo + m11 * x_lo + m12;
    const float cx01 = m10 * y_lo + m11 * x_hi + m12;
    const float cx10 = m10 * y_hi + m11 * x_lo + m12;
    const float cx11 = m10 * y_hi + m11 * x_hi + m12;
    const float miny = fminf(fminf(cy00, cy01), fminf(cy10, cy11));
    const float maxy = fmaxf(fmaxf(cy00, cy01), fmaxf(cy10, cy11));
    const float minx = fminf(fminf(cx00, cx01), fminf(cx10, cx11));
    const float maxx = fmaxf(fmaxf(cx00, cx01), fmaxf(cx10, cx11));
    const bool interior = (miny >= 0.01f) && (maxy <= 510.9f) &&
                          (minx >= 0.01f) && (maxx <= 510.9f);

    // ---- Stage 1: warp 40x40 window into LDS (bilinear gather, zero pad) ----
    if (interior) {
        for (int e = tid; e < WIN * WIN; e += THREADS) {
            const int r = e / WIN;
            const int c = e - r * WIN;
            const float yf = (float)(jy0 + r);
            const float xf = (float)(jx0 + c);
            const float src_y = m00 * yf + m01 * xf + m02;
            const float src_x = m10 * yf + m11 * xf + m12;
            const float fy0 = floorf(src_y);
            const float fx0 = floorf(src_x);
            const float fy  = src_y - fy0;
            const float fx  = src_x - fx0;
            const int off = ((int)fy0 * W + (int)fx0) * 3;
            const float* p0 = imgb + off;       // 6 consecutive floats (2 px)
            const float* p1 = p0 + W * 3;
            const float a0 = p0[0], a1 = p0[1], a2 = p0[2];
            const float a3 = p0[3], a4 = p0[4], a5 = p0[5];
            const float b0 = p1[0], b1 = p1[1], b2 = p1[2];
            const float b3 = p1[3], b4 = p1[4], b5 = p1[5];
            const float w00 = (1.0f - fy) * (1.0f - fx);
            const float w01 = (1.0f - fy) * fx;
            const float w10 = fy * (1.0f - fx);
            const float w11 = fy * fx;
            const float c0 = a0 * w00 + a3 * w01 + b0 * w10 + b3 * w11;
            const float c1 = a1 * w00 + a4 * w01 + b1 * w10 + b4 * w11;
            const float c2 = a2 * w00 + a5 * w01 + b2 * w10 + b5 * w11;
            uint2 q; q.x = pack_bf2(c0, c1); q.y = pack_bf1(c2);
            sW[r][c] = q;
        }
    } else {
        for (int e = tid; e < WIN * WIN; e += THREADS) {
            const int r = e / WIN;
            const int c = e - r * WIN;
            const float yf = (float)(jy0 + r);
            const float xf = (float)(jx0 + c);
            const float src_y = m00 * yf + m01 * xf + m02;
            const float src_x = m10 * yf + m11 * xf + m12;
            const float fy0 = floorf(src_y);
            const float fx0 = floorf(src_x);
            const float fy  = src_y - fy0;
            const float fx  = src_x - fx0;
            const int iy0 = (int)fy0;
            const int ix0 = (int)fx0;
            float v[4][3];
#pragma unroll
            for (int t = 0; t < 4; ++t) {
                const int yi = iy0 + (t >> 1);
                const int xi = ix0 + (t & 1);
                if (yi >= 0 && yi < H && xi >= 0 && xi < W) {
                    const float* p = imgb + (yi * W + xi) * 3;
                    v[t][0] = p[0]; v[t][1] = p[1]; v[t][2] = p[2];
                } else {
                    v[t][0] = 0.0f; v[t][1] = 0.0f; v[t][2] = 0.0f;
                }
            }
            const float w00 = (1.0f - fy) * (1.0f - fx);
            const float w01 = (1.0f - fy) * fx;
            const float w10 = fy * (1.0f - fx);
            const float w11 = fy * fx;
            const float c0 = v[0][0] * w00 + v[1][0] * w01 + v[2][0] * w10 + v[3][0] * w11;
            const float c1 = v[0][1] * w00 + v[1][1] * w01 + v[2][1] * w10 + v[3][1] * w11;
            const float c2 = v[0][2] * w00 + v[1][2] * w01 + v[2][2] * w10 + v[3][2] * w11;
            uint2 q; q.x = pack_bf2(c0, c1); q.y = pack_bf1(c2);
            sW[r][c] = q;
        }
    }
    __syncthreads();

    // ---- Stage 2: vertical 5-tap resize -> sV[16][40] (packed) ----
    for (int e = tid; e < TILE * WIN; e += THREADS) {
        const int r = e / WIN;               // local output row
        const int c = e - r * WIN;           // window column
        const int rr0 = jyt[r];
        float a0 = 0.0f, a1 = 0.0f, a2 = 0.0f;
#pragma unroll
        for (int k = 0; k < 5; ++k) {
            const uint2 q = sW[rr0 + k][c];
            const float wv = wyt[r][k];
            a0 += wv * lo_bf(q.x);
            a1 += wv * hi_bf(q.x);
            a2 += wv * lo_bf(q.y);
        }
        uint2 q; q.x = pack_bf2(a0, a1); q.y = pack_bf1(a2);
        sV[r][c] = q;
    }
    __syncthreads();

    // ---- Stage 3: horizontal 5-tap, one thread per output pixel (256 exact) ----
    {
        const int oxl = tid & (TILE - 1);
        const int oyl = tid >> 4;
        const int cc0 = jxt[oxl];
        float a0 = 0.0f, a1 = 0.0f, a2 = 0.0f;
#pragma unroll
        for (int k = 0; k < 5; ++k) {
            const uint2 q = sV[oyl][cc0 + k];
            const float wv = wxt[oxl][k];
            a0 += wv * lo_bf(q.x);
            a1 += wv * hi_bf(q.x);
            a2 += wv * lo_bf(q.y);
        }
        const int ox = ox_base + oxl;
        const int oy = oy_base + oyl;
        float* o = out + (((size_t)b * OH + oy) * OW + ox) * 3;
        o[0] = a0;
        o[1] = a1;
        o[2] = a2;
    }
}

extern "C" void kernel_launch(void* const* d_in, const int* in_sizes, int n_in,
                              void* d_out, int out_size, void* d_ws, size_t ws_size,
                              hipStream_t stream) {
    const float* img  = (const float*)d_in[0];
    const float* mats = (const float*)d_in[1];
    float*       out  = (float*)d_out;

    hipLaunchKernelGGL(warp_resize_tiled, dim3(NB), dim3(THREADS), 0, stream, img, mats, out);
}